// Round 6
// baseline (234.221 us; speedup 1.0000x reference)
//
#include <hip/hip_runtime.h>

// QuantumLayer: B=8, L=2048, D=512, NQ=10, 4 layers, DIM=1024.
// One wave per token. State packed as float2: amplitude index i (10 bits):
//   lane = i>>4 (bits 9..4), reg r = i&15; r = 2*j + e (j = v2f idx, e = elem)
// qubit q sits at bit 9-q: q0..q5 -> lane bits 5..0; q6 -> j bit2,
// q7 -> j bit1, q8 -> j bit0, q9 -> element.
//
// Per layer/qubit RX(f)->phase(f)->RY(w0)->RZ(w1) fuse into one SU(2) gate
// U = [[a,-conj b],[b,conj a]], (ar,ai,br,bi) = Q0 + A*Q1 + C*Q2 with
// A=c^2, C=c*s. Q* are weight-only, precomputed by a tiny prep kernel into
// d_ws (along with transposed out_W) so the main kernel uses ZERO LDS
// (no __shared__, no barriers) -> occupancy limited only by VGPRs.
#define NQ 10
#define DQ 512
#define QL 4
#define NTOK (8 * 2048)
#define QOFF (NQ * DQ)   // float offset of Q tables inside ws

typedef float v2f __attribute__((ext_vector_type(2)));
typedef float v4f __attribute__((ext_vector_type(4)));

// ---- cross-lane xor-M: DPP for 1/2/8, __shfl_xor for 4/16/32 (HW-proven) ---
template <int CTRL>
__device__ __forceinline__ float dppf(float v) {
    int i = __builtin_bit_cast(int, v);
    i = __builtin_amdgcn_update_dpp(i, i, CTRL, 0xF, 0xF, false);
    return __builtin_bit_cast(float, i);
}
template <int M>
__device__ __forceinline__ float lx(float v) {
    if constexpr (M == 1)      return dppf<0xB1>(v);   // quad_perm [1,0,3,2]
    else if constexpr (M == 2) return dppf<0x4E>(v);   // quad_perm [2,3,0,1]
    else if constexpr (M == 8) return dppf<0x128>(v);  // row_ror:8 == xor 8
    else return __shfl_xor(v, M);
}
template <int M>
__device__ __forceinline__ v2f lx2(v2f v) {
    v2f r; r.x = lx<M>(v.x); r.y = lx<M>(v.y); return r;
}

__device__ __forceinline__ void reduce10(float* z) {
#pragma unroll
    for (int q = 0; q < NQ; ++q) {
        z[q] += lx<32>(z[q]); z[q] += lx<16>(z[q]); z[q] += lx<8>(z[q]);
        z[q] += lx<4>(z[q]);  z[q] += lx<2>(z[q]);  z[q] += lx<1>(z[q]);
    }
}

// coef = Q0 + A*Q1 + C*Q2  ->  (ar, ai, br, bi)
__device__ __forceinline__ v4f coef(const v4f* Q, float c, float s) {
    float A = c * c, C = c * s;
    return Q[0] + A * Q[1] + C * Q[2];
}

// ---- general SU(2) gate application (R5-verified math) ---------------------
template <int M>
__device__ __forceinline__ void gate_lane(v2f* sr2, v2f* si2, v4f cf, bool bit) {
    const float ar = cf.x;
    const float Ai = bit ? -cf.y : cf.y;
    const float Br = bit ? cf.z : -cf.z;
    const float bi = cf.w;
#pragma unroll
    for (int j = 0; j < 8; ++j) {
        v2f wr = lx2<M>(sr2[j]), wi = lx2<M>(si2[j]);
        v2f nr = ar * sr2[j] - Ai * si2[j] + Br * wr - bi * wi;
        v2f ni = ar * si2[j] + Ai * sr2[j] + Br * wi + bi * wr;
        sr2[j] = nr; si2[j] = ni;
    }
}
template <int BJ>
__device__ __forceinline__ void gate_reg(v2f* sr2, v2f* si2, v4f cf) {
    const float ar = cf.x, ai = cf.y, br = cf.z, bi = cf.w;
#pragma unroll
    for (int j = 0; j < 8; ++j) if (!(j & BJ)) {
        const int j1 = j | BJ;
        v2f x0r = sr2[j], x0i = si2[j], x1r = sr2[j1], x1i = si2[j1];
        sr2[j]  = ar * x0r - ai * x0i - br * x1r - bi * x1i;
        si2[j]  = ar * x0i + ai * x0r - br * x1i + bi * x1r;
        sr2[j1] = br * x0r - bi * x0i + ar * x1r + ai * x1i;
        si2[j1] = br * x0i + bi * x0r + ar * x1i - ai * x1r;
    }
}
__device__ __forceinline__ void gate_elem(v2f* sr2, v2f* si2, v4f cf) {
    const float ar = cf.x, ai = cf.y, br = cf.z, bi = cf.w;
    const v2f cA = {ar, br}, cB = {-ai, -bi}, cC = {-br, ar}, cD = {-bi, ai};
    const v2f cF = {ai, bi}, cH = {bi, -ai};
#pragma unroll
    for (int j = 0; j < 8; ++j) {
        float x0r = sr2[j].x, x0i = si2[j].x, x1r = sr2[j].y, x1i = si2[j].y;
        v2f nr = x0r * cA + x0i * cB + x1r * cC + x1i * cD;
        v2f ni = x0i * cA + x0r * cF + x1i * cC + x1r * cH;
        sr2[j] = nr; si2[j] = ni;
    }
}

// CNOT q=6,7,8 composed register permutation, cycle form (R4/R5-proven)
__device__ __forceinline__ void perm678(v2f* a) {
    float t;
    t = a[1].x; a[1].x = a[1].y; a[1].y = t;
    t = a[2].x; a[2].x = a[3].x; a[3].x = a[2].y; a[2].y = a[3].y; a[3].y = t;
    t = a[4].x; a[4].x = a[6].x; a[6].x = a[5].x; a[5].x = a[7].y; a[7].y = t;
    t = a[4].y; a[4].y = a[6].y; a[6].y = a[5].y; a[5].y = a[7].x; a[7].x = t;
}

// ring CNOTs q -> q+1 (mod 10) (R4/R5-proven)
__device__ __forceinline__ void cnot_ring(v2f* sr2, v2f* si2, int lane, int srcl) {
#pragma unroll
    for (int j = 0; j < 8; ++j) {
        sr2[j].x = __shfl(sr2[j].x, srcl); sr2[j].y = __shfl(sr2[j].y, srcl);
        si2[j].x = __shfl(si2[j].x, srcl); si2[j].y = __shfl(si2[j].y, srcl);
    }
    {
        const bool ctrl = (lane & 1);
#pragma unroll
        for (int j = 0; j < 4; ++j) {
            v2f t0 = sr2[j], t1 = sr2[j + 4];
            sr2[j]     = ctrl ? t1 : t0;
            sr2[j + 4] = ctrl ? t0 : t1;
            t0 = si2[j]; t1 = si2[j + 4];
            si2[j]     = ctrl ? t1 : t0;
            si2[j + 4] = ctrl ? t0 : t1;
        }
    }
    perm678(sr2);
    perm678(si2);
#pragma unroll
    for (int j = 0; j < 8; ++j) {
        sr2[j].y = __shfl_xor(sr2[j].y, 32);
        si2[j].y = __shfl_xor(si2[j].y, 32);
    }
}

// ---- prep kernel: transposed out_W + weight-only Q tables into d_ws --------
__global__ __launch_bounds__(512) void prep_kernel(
    const float* __restrict__ weights, const float* __restrict__ out_W,
    float* __restrict__ ws)
{
    const int t = threadIdx.x;   // 512 threads
#pragma unroll
    for (int q = 0; q < NQ; ++q)
        ws[q * DQ + t] = out_W[t * NQ + q];
    if (t < QL * NQ) {
        float w0 = weights[t * 2], w1 = weights[t * 2 + 1];
        float cy = __cosf(0.5f * w0), sy = __sinf(0.5f * w0);
        float cz = __cosf(0.5f * w1), sz = __sinf(0.5f * w1);
        float d = cy - sy, e = cy + sy;
        v4f* Q = (v4f*)(ws + QOFF);
        Q[t * 3 + 0] = (v4f){-cz * sy,  sz * sy,  cz * cy,  sz * cy};
        Q[t * 3 + 1] = (v4f){ cz * e,  -sz * e,  -cz * d,  -sz * d};
        Q[t * 3 + 2] = (v4f){-sz * d,  -cz * d,   sz * e,  -cz * e};
    }
}

__global__ __launch_bounds__(256) void quantum_kernel(
    const float* __restrict__ x, const float* __restrict__ in_W,
    const float* __restrict__ in_b, const float* __restrict__ gamma,
    const float* __restrict__ beta, const float* __restrict__ ws,
    const float* __restrict__ out_b, float* __restrict__ out)
{
    const int t = threadIdx.x;
    const int lane = t & 63;
    const int tok = blockIdx.x * 4 + (t >> 6);
    const v4f* Qg = (const v4f*)(ws + QOFF);   // wave-uniform -> s_load path

    // composed CNOT lane permutation (q0..4) source lane, hoisted
    int srcl = lane;
#pragma unroll
    for (int q = 4; q >= 0; --q) {
        const int bc = 5 - q, bt = bc - 1;
        srcl ^= ((srcl >> bc) & 1) << bt;
    }

    // ---------------- stage 1: h = tanh(x @ in_W^T + in_b), then LN ----------
    const v2f* xrow2 = (const v2f*)(x + (size_t)tok * DQ);
    const v2f* inW2 = (const v2f*)in_W;
    v2f hv[NQ];
#pragma unroll
    for (int q = 0; q < NQ; ++q) hv[q] = (v2f){0.f, 0.f};
#pragma unroll
    for (int k = 0; k < 4; ++k) {
        v2f xk = xrow2[lane + 64 * k];
#pragma unroll
        for (int q = 0; q < NQ; ++q)
            hv[q] = xk * inW2[q * (DQ / 2) + lane + 64 * k] + hv[q];
    }
    float h[NQ];
#pragma unroll
    for (int q = 0; q < NQ; ++q) h[q] = hv[q].x + hv[q].y;
    reduce10(h);

    float mu = 0.f;
#pragma unroll
    for (int q = 0; q < NQ; ++q) {
        float e = __expf(2.f * (h[q] + in_b[q]));
        h[q] = (e - 1.f) * __builtin_amdgcn_rcpf(e + 1.f);
        mu += h[q];
    }
    mu *= 0.1f;
    float var = 0.f;
#pragma unroll
    for (int q = 0; q < NQ; ++q) { float d0 = h[q] - mu; var += d0 * d0; }
    var *= 0.1f;
    const float rstd = rsqrtf(var + 1e-5f);

    float cq[NQ], sq[NQ];
#pragma unroll
    for (int q = 0; q < NQ; ++q) {
        float f = (h[q] - mu) * rstd * gamma[q] + beta[q];
        float hf = 0.5f * f;
        cq[q] = __cosf(hf);
        sq[q] = __sinf(hf);
    }

    // ---------------- layer 0: product state built directly -----------------
    v2f sr2[8], si2[8];
    {
        const v4f* Q0 = Qg;
        v4f f0 = coef(Q0 + 0, cq[0], sq[0]);
        bool b0 = (lane & 32);
        float Lr = b0 ? f0.z : f0.x, Li = b0 ? f0.w : f0.y;
#pragma unroll
        for (int q = 1; q < 6; ++q) {
            v4f f = coef(Q0 + 3 * q, cq[q], sq[q]);
            bool b = lane & (1 << (5 - q));
            float fr = b ? f.z : f.x, fi = b ? f.w : f.y;
            float nr = Lr * fr - Li * fi, ni = Lr * fi + Li * fr;
            Lr = nr; Li = ni;
        }
        float Pr[8], Pi[8];
        {   // q6 -> j bit2
            v4f f6 = coef(Q0 + 18, cq[6], sq[6]);
            Pr[0] = Lr * f6.x - Li * f6.y; Pi[0] = Lr * f6.y + Li * f6.x;
            Pr[4] = Lr * f6.z - Li * f6.w; Pi[4] = Lr * f6.w + Li * f6.z;
        }
        {   // q7 -> j bit1
            v4f f7 = coef(Q0 + 21, cq[7], sq[7]);
#pragma unroll
            for (int jj = 0; jj < 8; jj += 4) {
                float tr1 = Pr[jj] * f7.z - Pi[jj] * f7.w;
                float ti1 = Pr[jj] * f7.w + Pi[jj] * f7.z;
                float tr0 = Pr[jj] * f7.x - Pi[jj] * f7.y;
                float ti0 = Pr[jj] * f7.y + Pi[jj] * f7.x;
                Pr[jj] = tr0; Pi[jj] = ti0; Pr[jj + 2] = tr1; Pi[jj + 2] = ti1;
            }
        }
        {   // q8 -> j bit0
            v4f f8 = coef(Q0 + 24, cq[8], sq[8]);
#pragma unroll
            for (int jj = 0; jj < 8; jj += 2) {
                float tr1 = Pr[jj] * f8.z - Pi[jj] * f8.w;
                float ti1 = Pr[jj] * f8.w + Pi[jj] * f8.z;
                float tr0 = Pr[jj] * f8.x - Pi[jj] * f8.y;
                float ti0 = Pr[jj] * f8.y + Pi[jj] * f8.x;
                Pr[jj] = tr0; Pi[jj] = ti0; Pr[jj + 1] = tr1; Pi[jj + 1] = ti1;
            }
        }
        {   // q9 -> element
            v4f f9 = coef(Q0 + 27, cq[9], sq[9]);
            v2f c9r = {f9.x, f9.z}, c9i = {f9.y, f9.w};
#pragma unroll
            for (int j = 0; j < 8; ++j) {
                sr2[j] = Pr[j] * c9r - Pi[j] * c9i;
                si2[j] = Pr[j] * c9i + Pi[j] * c9r;
            }
        }
    }
    cnot_ring(sr2, si2, lane, srcl);

    // ---------------- layers 1..3: one fused SU(2) gate per qubit ------------
#pragma unroll 1
    for (int l = 1; l < QL; ++l) {
        const v4f* Ql = Qg + l * NQ * 3;
        gate_lane<32>(sr2, si2, coef(Ql + 0,  cq[0], sq[0]), lane & 32);
        gate_lane< 8>(sr2, si2, coef(Ql + 6,  cq[2], sq[2]), lane & 8);
        gate_lane<16>(sr2, si2, coef(Ql + 3,  cq[1], sq[1]), lane & 16);
        gate_lane< 2>(sr2, si2, coef(Ql + 12, cq[4], sq[4]), lane & 2);
        gate_lane< 4>(sr2, si2, coef(Ql + 9,  cq[3], sq[3]), lane & 4);
        gate_lane< 1>(sr2, si2, coef(Ql + 15, cq[5], sq[5]), lane & 1);
        gate_reg<4>(sr2, si2, coef(Ql + 18, cq[6], sq[6]));
        gate_reg<2>(sr2, si2, coef(Ql + 21, cq[7], sq[7]));
        gate_reg<1>(sr2, si2, coef(Ql + 24, cq[8], sq[8]));
        gate_elem(sr2, si2, coef(Ql + 27, cq[9], sq[9]));
        cnot_ring(sr2, si2, lane, srcl);
    }

    // ---------------- measurement -------------------------------------------
    v2f aP = {0.f, 0.f}, a6 = {0.f, 0.f}, a7 = {0.f, 0.f}, a8 = {0.f, 0.f};
#pragma unroll
    for (int j = 0; j < 8; ++j) {
        v2f p = sr2[j] * sr2[j] + si2[j] * si2[j];
        aP += p;
        if (j & 4) a6 -= p; else a6 += p;
        if (j & 2) a7 -= p; else a7 += p;
        if (j & 1) a8 -= p; else a8 += p;
    }
    const float P = aP.x + aP.y;
    float z[NQ];
#pragma unroll
    for (int q = 0; q < 6; ++q)
        z[q] = (lane & (1 << (5 - q))) ? -P : P;
    z[6] = a6.x + a6.y; z[7] = a7.x + a7.y; z[8] = a8.x + a8.y;
    z[9] = aP.x - aP.y;
    reduce10(z);

    // ---------------- epilogue: out = x + z @ out_W^T + out_b ----------------
    v2f* orow2 = (v2f*)(out + (size_t)tok * DQ);
    const v2f* ob2 = (const v2f*)out_b;
    const v2f* oWt2 = (const v2f*)ws;   // transposed out_W [q][d]
#pragma unroll
    for (int k = 0; k < 4; ++k) {
        const int d2 = lane + 64 * k;
        v2f acc = xrow2[d2] + ob2[d2];
#pragma unroll
        for (int q = 0; q < NQ; ++q)
            acc = z[q] * oWt2[q * (DQ / 2) + d2] + acc;
        orow2[d2] = acc;
    }
}

extern "C" void kernel_launch(void* const* d_in, const int* in_sizes, int n_in,
                              void* d_out, int out_size, void* d_ws, size_t ws_size,
                              hipStream_t stream) {
    const float* x       = (const float*)d_in[0];
    const float* in_W    = (const float*)d_in[1];
    const float* in_b    = (const float*)d_in[2];
    const float* gamma   = (const float*)d_in[3];
    const float* beta    = (const float*)d_in[4];
    const float* weights = (const float*)d_in[5];
    const float* out_W   = (const float*)d_in[6];
    const float* out_b   = (const float*)d_in[7];
    float* out = (float*)d_out;
    float* ws = (float*)d_ws;

    hipLaunchKernelGGL(prep_kernel, dim3(1), dim3(512), 0, stream,
                       weights, out_W, ws);
    hipLaunchKernelGGL(quantum_kernel, dim3(NTOK / 4), dim3(256), 0, stream,
                       x, in_W, in_b, gamma, beta, ws, out_b, out);
}

// Round 7
// 198.838 us; speedup vs baseline: 1.1779x; 1.1779x over previous
//
#include <hip/hip_runtime.h>

// QuantumLayer: B=8, L=2048, D=512, NQ=10, 4 layers, DIM=1024.
// One wave per token. Statevector packed as half2: amplitude index i (10 bits):
//   lane = i>>4 (bits 9..4), reg r = i&15; r = 2*j + e (j = VGPR idx, e = half)
// qubit q sits at bit 9-q: q0..q5 -> lane bits 5..0; q6 -> j bit2,
// q7 -> j bit1, q8 -> j bit0, q9 -> element(half).
//
// Per layer/qubit RX(f)->phase(f)->RY(w0)->RZ(w1) fuse into one SU(2) gate
// U = [[a,-conj b],[b,conj a]], (ar,ai,br,bi) = Q0 + A*Q1 + C*Q2, A=c^2,
// C=c*s; Q* weight-only, precomputed into d_ws. State in f16: halves every
// cross-lane DS op (one 32-bit bpermute moves 2 amplitudes) and halves the
// state register footprint. Angle math / reductions / epilogue stay fp32.
#define NQ 10
#define DQ 512
#define QL 4
#define NTOK (8 * 2048)
#define QOFF (NQ * DQ)   // float offset of Q tables inside ws

typedef float v2f __attribute__((ext_vector_type(2)));
typedef float v4f __attribute__((ext_vector_type(4)));
typedef _Float16 h2 __attribute__((ext_vector_type(2)));

// ---- cross-lane xor-M on 32-bit payloads: DPP 1/2/8, shfl_xor 4/16/32 ------
template <int CTRL>
__device__ __forceinline__ int dppi(int i) {
    return __builtin_amdgcn_update_dpp(i, i, CTRL, 0xF, 0xF, false);
}
template <int M>
__device__ __forceinline__ int lxi(int i) {
    if constexpr (M == 1)      return dppi<0xB1>(i);   // quad_perm [1,0,3,2]
    else if constexpr (M == 2) return dppi<0x4E>(i);   // quad_perm [2,3,0,1]
    else if constexpr (M == 8) return dppi<0x128>(i);  // row_ror:8 == xor 8
    else return __shfl_xor(i, M);
}
template <int M>
__device__ __forceinline__ float lx(float v) {
    return __builtin_bit_cast(float, lxi<M>(__builtin_bit_cast(int, v)));
}
template <int M>
__device__ __forceinline__ h2 lxh(h2 v) {
    return __builtin_bit_cast(h2, lxi<M>(__builtin_bit_cast(int, v)));
}

__device__ __forceinline__ void reduce10(float* z) {
#pragma unroll
    for (int q = 0; q < NQ; ++q) {
        z[q] += lx<32>(z[q]); z[q] += lx<16>(z[q]); z[q] += lx<8>(z[q]);
        z[q] += lx<4>(z[q]);  z[q] += lx<2>(z[q]);  z[q] += lx<1>(z[q]);
    }
}

// coef = Q0 + A*Q1 + C*Q2  ->  (ar, ai, br, bi)  (fp32)
__device__ __forceinline__ v4f coef(const v4f* Q, float c, float s) {
    float A = c * c, C = c * s;
    return Q[0] + A * Q[1] + C * Q[2];
}

__device__ __forceinline__ h2 h2bc(float v) {
    _Float16 h = (_Float16)v; return (h2){h, h};
}
__device__ __forceinline__ h2 h2swap(h2 v) {
    return __builtin_shufflevector(v, v, 1, 0);
}

// ---- SU(2) gate application on f16-packed state ----------------------------
template <int M>
__device__ __forceinline__ void gate_lane_h(h2* sr, h2* si, v4f cf, bool bit) {
    const float aif = bit ? -cf.y : cf.y;
    const float brf = bit ? cf.z : -cf.z;
    const h2 ar = h2bc(cf.x), ai = h2bc(aif), br = h2bc(brf), bi = h2bc(cf.w);
#pragma unroll
    for (int j = 0; j < 8; ++j) {
        h2 wr = lxh<M>(sr[j]), wi = lxh<M>(si[j]);
        h2 nr = ar * sr[j] - ai * si[j] + br * wr - bi * wi;
        h2 ni = ar * si[j] + ai * sr[j] + br * wi + bi * wr;
        sr[j] = nr; si[j] = ni;
    }
}
template <int BJ>
__device__ __forceinline__ void gate_reg_h(h2* sr, h2* si, v4f cf) {
    const h2 ar = h2bc(cf.x), ai = h2bc(cf.y), br = h2bc(cf.z), bi = h2bc(cf.w);
#pragma unroll
    for (int j = 0; j < 8; ++j) if (!(j & BJ)) {
        const int j1 = j | BJ;
        h2 x0r = sr[j], x0i = si[j], x1r = sr[j1], x1i = si[j1];
        sr[j]  = ar * x0r - ai * x0i - br * x1r - bi * x1i;
        si[j]  = ar * x0i + ai * x0r - br * x1i + bi * x1r;
        sr[j1] = br * x0r - bi * x0i + ar * x1r + ai * x1i;
        si[j1] = br * x0i + bi * x0r + ar * x1i - ai * x1r;
    }
}
__device__ __forceinline__ void gate_elem_h(h2* sr, h2* si, v4f cf) {
    const h2 ar = h2bc(cf.x), bi = h2bc(cf.w);
    const h2 aiV = (h2){(_Float16)cf.y, (_Float16)(-cf.y)};
    const h2 brV = (h2){(_Float16)(-cf.z), (_Float16)cf.z};
#pragma unroll
    for (int j = 0; j < 8; ++j) {
        h2 swr = h2swap(sr[j]), swi = h2swap(si[j]);
        h2 nr = ar * sr[j] - aiV * si[j] + brV * swr - bi * swi;
        h2 ni = ar * si[j] + aiV * sr[j] + brV * swi + bi * swr;
        sr[j] = nr; si[j] = ni;
    }
}

// CNOT q=6,7,8 composed register permutation in h2 form (derived from the
// R4-proven scalar cycles): j1=swap(j1); (j2,j3)=(j3,swap(j2));
// (j4,j5,j6,j7)=(j6, swap(j7), j5, swap(j4)).
__device__ __forceinline__ void perm678_h(h2* a) {
    h2 o2 = a[2], o4 = a[4], o7 = a[7];
    a[1] = h2swap(a[1]);
    a[2] = a[3]; a[3] = h2swap(o2);
    a[4] = a[6]; a[6] = a[5]; a[5] = h2swap(o7); a[7] = h2swap(o4);
}

// ring CNOTs q -> q+1 (mod 10) on f16-packed state
__device__ __forceinline__ void cnot_ring_h(h2* sr, h2* si, int lane, int srcl) {
    // q=0..4: one composed lane permutation
#pragma unroll
    for (int j = 0; j < 8; ++j) {
        sr[j] = __builtin_bit_cast(h2, __shfl(__builtin_bit_cast(int, sr[j]), srcl));
        si[j] = __builtin_bit_cast(h2, __shfl(__builtin_bit_cast(int, si[j]), srcl));
    }
    // q=5: control = lane bit0, target = j bit2
    {
        const bool ctrl = (lane & 1);
#pragma unroll
        for (int j = 0; j < 4; ++j) {
            h2 t0 = sr[j], t1 = sr[j + 4];
            sr[j] = ctrl ? t1 : t0; sr[j + 4] = ctrl ? t0 : t1;
            t0 = si[j]; t1 = si[j + 4];
            si[j] = ctrl ? t1 : t0; si[j + 4] = ctrl ? t0 : t1;
        }
    }
    perm678_h(sr);
    perm678_h(si);
    // q=9: control = element bit (high half), target = lane bit5
#pragma unroll
    for (int j = 0; j < 8; ++j) {
        h2 w = lxh<32>(sr[j]); sr[j] = (h2){sr[j].x, w.y};
        w = lxh<32>(si[j]);    si[j] = (h2){si[j].x, w.y};
    }
}

// ---- prep kernel: transposed out_W + weight-only Q tables into d_ws --------
__global__ __launch_bounds__(512) void prep_kernel(
    const float* __restrict__ weights, const float* __restrict__ out_W,
    float* __restrict__ ws)
{
    const int t = threadIdx.x;   // 512 threads
#pragma unroll
    for (int q = 0; q < NQ; ++q)
        ws[q * DQ + t] = out_W[t * NQ + q];
    if (t < QL * NQ) {
        float w0 = weights[t * 2], w1 = weights[t * 2 + 1];
        float cy = __cosf(0.5f * w0), sy = __sinf(0.5f * w0);
        float cz = __cosf(0.5f * w1), sz = __sinf(0.5f * w1);
        float d = cy - sy, e = cy + sy;
        v4f* Q = (v4f*)(ws + QOFF);
        Q[t * 3 + 0] = (v4f){-cz * sy,  sz * sy,  cz * cy,  sz * cy};
        Q[t * 3 + 1] = (v4f){ cz * e,  -sz * e,  -cz * d,  -sz * d};
        Q[t * 3 + 2] = (v4f){-sz * d,  -cz * d,   sz * e,  -cz * e};
    }
}

__global__ __launch_bounds__(256) void quantum_kernel(
    const float* __restrict__ x, const float* __restrict__ in_W,
    const float* __restrict__ in_b, const float* __restrict__ gamma,
    const float* __restrict__ beta, const float* __restrict__ ws,
    const float* __restrict__ out_b, float* __restrict__ out)
{
    const int t = threadIdx.x;
    const int lane = t & 63;
    const int tok = blockIdx.x * 4 + (t >> 6);
    const v4f* Qg = (const v4f*)(ws + QOFF);   // wave-uniform -> s_load path

    // composed CNOT lane permutation (q0..4) source lane, hoisted
    int srcl = lane;
#pragma unroll
    for (int q = 4; q >= 0; --q) {
        const int bc = 5 - q, bt = bc - 1;
        srcl ^= ((srcl >> bc) & 1) << bt;
    }

    // ---------------- stage 1: h = tanh(x @ in_W^T + in_b), then LN ----------
    const v2f* xrow2 = (const v2f*)(x + (size_t)tok * DQ);
    const v2f* inW2 = (const v2f*)in_W;
    v2f hv[NQ];
#pragma unroll
    for (int q = 0; q < NQ; ++q) hv[q] = (v2f){0.f, 0.f};
#pragma unroll
    for (int k = 0; k < 4; ++k) {
        v2f xk = xrow2[lane + 64 * k];
#pragma unroll
        for (int q = 0; q < NQ; ++q)
            hv[q] = xk * inW2[q * (DQ / 2) + lane + 64 * k] + hv[q];
    }
    float h[NQ];
#pragma unroll
    for (int q = 0; q < NQ; ++q) h[q] = hv[q].x + hv[q].y;
    reduce10(h);

    float mu = 0.f;
#pragma unroll
    for (int q = 0; q < NQ; ++q) {
        float e = __expf(2.f * (h[q] + in_b[q]));
        h[q] = (e - 1.f) * __builtin_amdgcn_rcpf(e + 1.f);
        mu += h[q];
    }
    mu *= 0.1f;
    float var = 0.f;
#pragma unroll
    for (int q = 0; q < NQ; ++q) { float d0 = h[q] - mu; var += d0 * d0; }
    var *= 0.1f;
    const float rstd = rsqrtf(var + 1e-5f);

    float cq[NQ], sq[NQ];
#pragma unroll
    for (int q = 0; q < NQ; ++q) {
        float f = (h[q] - mu) * rstd * gamma[q] + beta[q];
        float hf = 0.5f * f;
        cq[q] = __cosf(hf);
        sq[q] = __sinf(hf);
    }

    // ---------------- layer 0: product state built directly (fp32) ----------
    h2 sr[8], si[8];
    {
        const v4f* Q0 = Qg;
        v4f f0 = coef(Q0 + 0, cq[0], sq[0]);
        bool b0 = (lane & 32);
        float Lr = b0 ? f0.z : f0.x, Li = b0 ? f0.w : f0.y;
#pragma unroll
        for (int q = 1; q < 6; ++q) {
            v4f f = coef(Q0 + 3 * q, cq[q], sq[q]);
            bool b = lane & (1 << (5 - q));
            float fr = b ? f.z : f.x, fi = b ? f.w : f.y;
            float nr = Lr * fr - Li * fi, ni = Lr * fi + Li * fr;
            Lr = nr; Li = ni;
        }
        float Pr[8], Pi[8];
        {   // q6 -> j bit2
            v4f f6 = coef(Q0 + 18, cq[6], sq[6]);
            Pr[0] = Lr * f6.x - Li * f6.y; Pi[0] = Lr * f6.y + Li * f6.x;
            Pr[4] = Lr * f6.z - Li * f6.w; Pi[4] = Lr * f6.w + Li * f6.z;
        }
        {   // q7 -> j bit1
            v4f f7 = coef(Q0 + 21, cq[7], sq[7]);
#pragma unroll
            for (int jj = 0; jj < 8; jj += 4) {
                float tr1 = Pr[jj] * f7.z - Pi[jj] * f7.w;
                float ti1 = Pr[jj] * f7.w + Pi[jj] * f7.z;
                float tr0 = Pr[jj] * f7.x - Pi[jj] * f7.y;
                float ti0 = Pr[jj] * f7.y + Pi[jj] * f7.x;
                Pr[jj] = tr0; Pi[jj] = ti0; Pr[jj + 2] = tr1; Pi[jj + 2] = ti1;
            }
        }
        {   // q8 -> j bit0
            v4f f8 = coef(Q0 + 24, cq[8], sq[8]);
#pragma unroll
            for (int jj = 0; jj < 8; jj += 2) {
                float tr1 = Pr[jj] * f8.z - Pi[jj] * f8.w;
                float ti1 = Pr[jj] * f8.w + Pi[jj] * f8.z;
                float tr0 = Pr[jj] * f8.x - Pi[jj] * f8.y;
                float ti0 = Pr[jj] * f8.y + Pi[jj] * f8.x;
                Pr[jj] = tr0; Pi[jj] = ti0; Pr[jj + 1] = tr1; Pi[jj + 1] = ti1;
            }
        }
        {   // q9 -> element: build packed f16 state directly
            v4f f9 = coef(Q0 + 27, cq[9], sq[9]);
#pragma unroll
            for (int j = 0; j < 8; ++j) {
                float e0r = Pr[j] * f9.x - Pi[j] * f9.y;
                float e0i = Pr[j] * f9.y + Pi[j] * f9.x;
                float e1r = Pr[j] * f9.z - Pi[j] * f9.w;
                float e1i = Pr[j] * f9.w + Pi[j] * f9.z;
                sr[j] = (h2){(_Float16)e0r, (_Float16)e1r};
                si[j] = (h2){(_Float16)e0i, (_Float16)e1i};
            }
        }
    }
    cnot_ring_h(sr, si, lane, srcl);

    // ---------------- layers 1..3: one fused SU(2) gate per qubit ------------
#pragma unroll
    for (int l = 1; l < QL; ++l) {
        const v4f* Ql = Qg + l * NQ * 3;
        gate_lane_h<32>(sr, si, coef(Ql + 0,  cq[0], sq[0]), lane & 32);
        gate_lane_h< 8>(sr, si, coef(Ql + 6,  cq[2], sq[2]), lane & 8);
        gate_lane_h<16>(sr, si, coef(Ql + 3,  cq[1], sq[1]), lane & 16);
        gate_lane_h< 2>(sr, si, coef(Ql + 12, cq[4], sq[4]), lane & 2);
        gate_lane_h< 4>(sr, si, coef(Ql + 9,  cq[3], sq[3]), lane & 4);
        gate_lane_h< 1>(sr, si, coef(Ql + 15, cq[5], sq[5]), lane & 1);
        gate_reg_h<4>(sr, si, coef(Ql + 18, cq[6], sq[6]));
        gate_reg_h<2>(sr, si, coef(Ql + 21, cq[7], sq[7]));
        gate_reg_h<1>(sr, si, coef(Ql + 24, cq[8], sq[8]));
        gate_elem_h(sr, si, coef(Ql + 27, cq[9], sq[9]));
        cnot_ring_h(sr, si, lane, srcl);
    }

    // ---------------- measurement (fp32) -------------------------------------
    v2f aP = {0.f, 0.f}, a6 = {0.f, 0.f}, a7 = {0.f, 0.f}, a8 = {0.f, 0.f};
#pragma unroll
    for (int j = 0; j < 8; ++j) {
        v2f rr = {(float)sr[j].x, (float)sr[j].y};
        v2f ii = {(float)si[j].x, (float)si[j].y};
        v2f p = rr * rr + ii * ii;
        aP += p;
        if (j & 4) a6 -= p; else a6 += p;
        if (j & 2) a7 -= p; else a7 += p;
        if (j & 1) a8 -= p; else a8 += p;
    }
    const float P = aP.x + aP.y;
    float z[NQ];
#pragma unroll
    for (int q = 0; q < 6; ++q)
        z[q] = (lane & (1 << (5 - q))) ? -P : P;
    z[6] = a6.x + a6.y; z[7] = a7.x + a7.y; z[8] = a8.x + a8.y;
    z[9] = aP.x - aP.y;
    reduce10(z);

    // ---------------- epilogue: out = x + z @ out_W^T + out_b ----------------
    v2f* orow2 = (v2f*)(out + (size_t)tok * DQ);
    const v2f* ob2 = (const v2f*)out_b;
    const v2f* oWt2 = (const v2f*)ws;   // transposed out_W [q][d]
#pragma unroll
    for (int k = 0; k < 4; ++k) {
        const int d2 = lane + 64 * k;
        v2f acc = xrow2[d2] + ob2[d2];
#pragma unroll
        for (int q = 0; q < NQ; ++q)
            acc = z[q] * oWt2[q * (DQ / 2) + d2] + acc;
        orow2[d2] = acc;
    }
}

extern "C" void kernel_launch(void* const* d_in, const int* in_sizes, int n_in,
                              void* d_out, int out_size, void* d_ws, size_t ws_size,
                              hipStream_t stream) {
    const float* x       = (const float*)d_in[0];
    const float* in_W    = (const float*)d_in[1];
    const float* in_b    = (const float*)d_in[2];
    const float* gamma   = (const float*)d_in[3];
    const float* beta    = (const float*)d_in[4];
    const float* weights = (const float*)d_in[5];
    const float* out_W   = (const float*)d_in[6];
    const float* out_b   = (const float*)d_in[7];
    float* out = (float*)d_out;
    float* ws = (float*)d_ws;

    hipLaunchKernelGGL(prep_kernel, dim3(1), dim3(512), 0, stream,
                       weights, out_W, ws);
    hipLaunchKernelGGL(quantum_kernel, dim3(NTOK / 4), dim3(256), 0, stream,
                       x, in_W, in_b, gamma, beta, ws, out_b, out);
}

// Round 8
// 195.528 us; speedup vs baseline: 1.1979x; 1.0169x over previous
//
#include <hip/hip_runtime.h>

// QuantumLayer: B=8, L=2048, D=512, NQ=10, 4 layers, DIM=1024.
// One wave per token. Statevector packed as half2: amplitude index i (10 bits):
//   lane = i>>4 (bits 9..4), reg r = i&15; r = 2*j + e (j = VGPR idx, e = half)
// qubit q at bit 9-q: q0..q5 -> lane bits 5..0; q6 -> j bit2, q7 -> j bit1,
// q8 -> j bit0, q9 -> element(half).
//
// Per layer/qubit RX(f)->phase(f)->RY(w0)->RZ(w1) fuse into one SU(2) gate
// (ar,ai,br,bi) = Q0 + A*Q1 + C*Q2, A=c^2, C=c*s; Q* weight-only (prep kernel
// -> d_ws). All shfl-class exchanges use ds_bpermute on 4 hoisted address
// regs; xor 1/2/8 use DPP. The FINAL CNOT ring is absorbed into measurement
// sign masks (ring = linear basis map; new bits are prefix-XORs).
#define NQ 10
#define DQ 512
#define QL 4
#define NTOK (8 * 2048)
#define QOFF (NQ * DQ)   // float offset of Q tables inside ws

typedef float v2f __attribute__((ext_vector_type(2)));
typedef float v4f __attribute__((ext_vector_type(4)));
typedef _Float16 h2 __attribute__((ext_vector_type(2)));

// ---- cross-lane helpers ----------------------------------------------------
__device__ __forceinline__ int bperm(int addr, int v) {
    return __builtin_amdgcn_ds_bpermute(addr, v);
}
__device__ __forceinline__ float bpermf(int addr, float v) {
    return __builtin_bit_cast(float, bperm(addr, __builtin_bit_cast(int, v)));
}
__device__ __forceinline__ h2 bpermh(int addr, h2 v) {
    return __builtin_bit_cast(h2, bperm(addr, __builtin_bit_cast(int, v)));
}
template <int CTRL>
__device__ __forceinline__ int dppi(int i) {
    return __builtin_amdgcn_update_dpp(i, i, CTRL, 0xF, 0xF, false);
}
template <int M>   // M in {1,2,8}
__device__ __forceinline__ float dppxf(float v) {
    int i = __builtin_bit_cast(int, v);
    if constexpr (M == 1)      i = dppi<0xB1>(i);   // quad_perm [1,0,3,2]
    else if constexpr (M == 2) i = dppi<0x4E>(i);   // quad_perm [2,3,0,1]
    else                       i = dppi<0x128>(i);  // row_ror:8 == xor 8
    return __builtin_bit_cast(float, i);
}
template <int M>
__device__ __forceinline__ h2 dppxh(h2 v) {
    return __builtin_bit_cast(h2, __builtin_bit_cast(float, v) * 0.f + 0.f), v; // unused
}

__device__ __forceinline__ void reduce10(float* z, int a32, int a16, int a4) {
#pragma unroll
    for (int q = 0; q < NQ; ++q) {
        z[q] += bpermf(a32, z[q]);
        z[q] += bpermf(a16, z[q]);
        z[q] += dppxf<8>(z[q]);
        z[q] += bpermf(a4, z[q]);
        z[q] += dppxf<2>(z[q]);
        z[q] += dppxf<1>(z[q]);
    }
}

// coef = Q0 + A*Q1 + C*Q2  ->  (ar, ai, br, bi)  (fp32)
__device__ __forceinline__ v4f coef(const v4f* Q, float A, float C) {
    return Q[0] + A * Q[1] + C * Q[2];
}
__device__ __forceinline__ h2 pk2(float a, float b) {
    return __builtin_bit_cast(h2, __builtin_amdgcn_cvt_pkrtz(a, b));
}
__device__ __forceinline__ h2 h2bc(float v) { return pk2(v, v); }
__device__ __forceinline__ h2 h2swap(h2 v) {
    return __builtin_shufflevector(v, v, 1, 0);
}

// ---- SU(2) gate application on f16-packed state ----------------------------
// lane-bit gate via bpermute (masks 4,16,32 with hoisted addr)
__device__ __forceinline__ void gate_lane_hp(h2* sr, h2* si, v4f cf, bool bit, int addr) {
    const float aif = bit ? -cf.y : cf.y;
    const float brf = bit ? cf.z : -cf.z;
    const h2 ar = h2bc(cf.x), ai = h2bc(aif), br = h2bc(brf), bi = h2bc(cf.w);
#pragma unroll
    for (int j = 0; j < 8; ++j) {
        h2 wr = bpermh(addr, sr[j]), wi = bpermh(addr, si[j]);
        h2 nr = ar * sr[j] - ai * si[j] + br * wr - bi * wi;
        h2 ni = ar * si[j] + ai * sr[j] + br * wi + bi * wr;
        sr[j] = nr; si[j] = ni;
    }
}
// lane-bit gate via DPP (masks 1,2,8)
template <int M>
__device__ __forceinline__ void gate_lane_hd(h2* sr, h2* si, v4f cf, bool bit) {
    const float aif = bit ? -cf.y : cf.y;
    const float brf = bit ? cf.z : -cf.z;
    const h2 ar = h2bc(cf.x), ai = h2bc(aif), br = h2bc(brf), bi = h2bc(cf.w);
#pragma unroll
    for (int j = 0; j < 8; ++j) {
        h2 wr, wi;
        {
            int iR = __builtin_bit_cast(int, sr[j]);
            int iI = __builtin_bit_cast(int, si[j]);
            if constexpr (M == 1)      { iR = dppi<0xB1>(iR);  iI = dppi<0xB1>(iI); }
            else if constexpr (M == 2) { iR = dppi<0x4E>(iR);  iI = dppi<0x4E>(iI); }
            else                       { iR = dppi<0x128>(iR); iI = dppi<0x128>(iI); }
            wr = __builtin_bit_cast(h2, iR); wi = __builtin_bit_cast(h2, iI);
        }
        h2 nr = ar * sr[j] - ai * si[j] + br * wr - bi * wi;
        h2 ni = ar * si[j] + ai * sr[j] + br * wi + bi * wr;
        sr[j] = nr; si[j] = ni;
    }
}
template <int BJ>
__device__ __forceinline__ void gate_reg_h(h2* sr, h2* si, v4f cf) {
    const h2 ar = h2bc(cf.x), ai = h2bc(cf.y), br = h2bc(cf.z), bi = h2bc(cf.w);
#pragma unroll
    for (int j = 0; j < 8; ++j) if (!(j & BJ)) {
        const int j1 = j | BJ;
        h2 x0r = sr[j], x0i = si[j], x1r = sr[j1], x1i = si[j1];
        sr[j]  = ar * x0r - ai * x0i - br * x1r - bi * x1i;
        si[j]  = ar * x0i + ai * x0r - br * x1i + bi * x1r;
        sr[j1] = br * x0r - bi * x0i + ar * x1r + ai * x1i;
        si[j1] = br * x0i + bi * x0r + ar * x1i - ai * x1r;
    }
}
__device__ __forceinline__ void gate_elem_h(h2* sr, h2* si, v4f cf) {
    const h2 ar = h2bc(cf.x), bi = h2bc(cf.w);
    const h2 aiV = pk2(cf.y, -cf.y);
    const h2 brV = pk2(-cf.z, cf.z);
#pragma unroll
    for (int j = 0; j < 8; ++j) {
        h2 swr = h2swap(sr[j]), swi = h2swap(si[j]);
        h2 nr = ar * sr[j] - aiV * si[j] + brV * swr - bi * swi;
        h2 ni = ar * si[j] + aiV * sr[j] + brV * swi + bi * swr;
        sr[j] = nr; si[j] = ni;
    }
}

// CNOT q=6,7,8 composed register permutation (R7-proven)
__device__ __forceinline__ void perm678_h(h2* a) {
    h2 o2 = a[2], o4 = a[4], o7 = a[7];
    a[1] = h2swap(a[1]);
    a[2] = a[3]; a[3] = h2swap(o2);
    a[4] = a[6]; a[6] = a[5]; a[5] = h2swap(o7); a[7] = h2swap(o4);
}

// ring CNOTs q -> q+1 (mod 10) on f16-packed state (bpermute addressing)
__device__ __forceinline__ void cnot_ring_h(h2* sr, h2* si, int lane, int apm, int a32) {
#pragma unroll
    for (int j = 0; j < 8; ++j) {
        sr[j] = bpermh(apm, sr[j]);
        si[j] = bpermh(apm, si[j]);
    }
    {
        const bool ctrl = (lane & 1);
#pragma unroll
        for (int j = 0; j < 4; ++j) {
            h2 t0 = sr[j], t1 = sr[j + 4];
            sr[j] = ctrl ? t1 : t0; sr[j + 4] = ctrl ? t0 : t1;
            t0 = si[j]; t1 = si[j + 4];
            si[j] = ctrl ? t1 : t0; si[j + 4] = ctrl ? t0 : t1;
        }
    }
    perm678_h(sr);
    perm678_h(si);
#pragma unroll
    for (int j = 0; j < 8; ++j) {
        h2 w = bpermh(a32, sr[j]); sr[j] = (h2){sr[j].x, w.y};
        w = bpermh(a32, si[j]);    si[j] = (h2){si[j].x, w.y};
    }
}

// ---- prep kernel: transposed out_W + weight-only Q tables into d_ws --------
__global__ __launch_bounds__(512) void prep_kernel(
    const float* __restrict__ weights, const float* __restrict__ out_W,
    float* __restrict__ ws)
{
    const int t = threadIdx.x;   // 512 threads
#pragma unroll
    for (int q = 0; q < NQ; ++q)
        ws[q * DQ + t] = out_W[t * NQ + q];
    if (t < QL * NQ) {
        float w0 = weights[t * 2], w1 = weights[t * 2 + 1];
        float cy = __cosf(0.5f * w0), sy = __sinf(0.5f * w0);
        float cz = __cosf(0.5f * w1), sz = __sinf(0.5f * w1);
        float d = cy - sy, e = cy + sy;
        v4f* Q = (v4f*)(ws + QOFF);
        Q[t * 3 + 0] = (v4f){-cz * sy,  sz * sy,  cz * cy,  sz * cy};
        Q[t * 3 + 1] = (v4f){ cz * e,  -sz * e,  -cz * d,  -sz * d};
        Q[t * 3 + 2] = (v4f){-sz * d,  -cz * d,   sz * e,  -cz * e};
    }
}

__global__ __launch_bounds__(256) void quantum_kernel(
    const float* __restrict__ x, const float* __restrict__ in_W,
    const float* __restrict__ in_b, const float* __restrict__ gamma,
    const float* __restrict__ beta, const float* __restrict__ ws,
    const float* __restrict__ out_b, float* __restrict__ out)
{
    const int t = threadIdx.x;
    const int lane = t & 63;
    const int tok = blockIdx.x * 4 + (t >> 6);
    const v4f* Qg = (const v4f*)(ws + QOFF);

    // hoisted bpermute byte addresses
    const int a32 = (lane ^ 32) << 2;
    const int a16 = (lane ^ 16) << 2;
    const int a4  = (lane ^ 4)  << 2;
    int srcl = lane;
#pragma unroll
    for (int q = 4; q >= 0; --q) {
        const int bc = 5 - q, bt = bc - 1;
        srcl ^= ((srcl >> bc) & 1) << bt;
    }
    const int apm = srcl << 2;

    // ---------------- stage 1: h = tanh(x @ in_W^T + in_b), then LN ----------
    const v2f* xrow2 = (const v2f*)(x + (size_t)tok * DQ);
    const v2f* inW2 = (const v2f*)in_W;
    v2f hv[NQ];
#pragma unroll
    for (int q = 0; q < NQ; ++q) hv[q] = (v2f){0.f, 0.f};
#pragma unroll
    for (int k = 0; k < 4; ++k) {
        v2f xk = xrow2[lane + 64 * k];
#pragma unroll
        for (int q = 0; q < NQ; ++q)
            hv[q] = xk * inW2[q * (DQ / 2) + lane + 64 * k] + hv[q];
    }
    float h[NQ];
#pragma unroll
    for (int q = 0; q < NQ; ++q) h[q] = hv[q].x + hv[q].y;
    reduce10(h, a32, a16, a4);

    float mu = 0.f;
#pragma unroll
    for (int q = 0; q < NQ; ++q) {
        float e = __expf(2.f * (h[q] + in_b[q]));
        h[q] = (e - 1.f) * __builtin_amdgcn_rcpf(e + 1.f);
        mu += h[q];
    }
    mu *= 0.1f;
    float var = 0.f;
#pragma unroll
    for (int q = 0; q < NQ; ++q) { float d0 = h[q] - mu; var += d0 * d0; }
    var *= 0.1f;
    const float rstd = rsqrtf(var + 1e-5f);

    float Aq[NQ], Cq[NQ];
#pragma unroll
    for (int q = 0; q < NQ; ++q) {
        float f = (h[q] - mu) * rstd * gamma[q] + beta[q];
        float hf = 0.5f * f;
        float c = __cosf(hf), s = __sinf(hf);
        Aq[q] = c * c;
        Cq[q] = c * s;
    }

    // ---------------- layer 0: product state built directly (fp32) ----------
    h2 sr[8], si[8];
    {
        const v4f* Q0 = Qg;
        v4f f0 = coef(Q0 + 0, Aq[0], Cq[0]);
        bool b0 = (lane & 32);
        float Lr = b0 ? f0.z : f0.x, Li = b0 ? f0.w : f0.y;
#pragma unroll
        for (int q = 1; q < 6; ++q) {
            v4f f = coef(Q0 + 3 * q, Aq[q], Cq[q]);
            bool b = lane & (1 << (5 - q));
            float fr = b ? f.z : f.x, fi = b ? f.w : f.y;
            float nr = Lr * fr - Li * fi, ni = Lr * fi + Li * fr;
            Lr = nr; Li = ni;
        }
        float Pr[8], Pi[8];
        {   // q6 -> j bit2
            v4f f6 = coef(Q0 + 18, Aq[6], Cq[6]);
            Pr[0] = Lr * f6.x - Li * f6.y; Pi[0] = Lr * f6.y + Li * f6.x;
            Pr[4] = Lr * f6.z - Li * f6.w; Pi[4] = Lr * f6.w + Li * f6.z;
        }
        {   // q7 -> j bit1
            v4f f7 = coef(Q0 + 21, Aq[7], Cq[7]);
#pragma unroll
            for (int jj = 0; jj < 8; jj += 4) {
                float tr1 = Pr[jj] * f7.z - Pi[jj] * f7.w;
                float ti1 = Pr[jj] * f7.w + Pi[jj] * f7.z;
                float tr0 = Pr[jj] * f7.x - Pi[jj] * f7.y;
                float ti0 = Pr[jj] * f7.y + Pi[jj] * f7.x;
                Pr[jj] = tr0; Pi[jj] = ti0; Pr[jj + 2] = tr1; Pi[jj + 2] = ti1;
            }
        }
        {   // q8 -> j bit0
            v4f f8 = coef(Q0 + 24, Aq[8], Cq[8]);
#pragma unroll
            for (int jj = 0; jj < 8; jj += 2) {
                float tr1 = Pr[jj] * f8.z - Pi[jj] * f8.w;
                float ti1 = Pr[jj] * f8.w + Pi[jj] * f8.z;
                float tr0 = Pr[jj] * f8.x - Pi[jj] * f8.y;
                float ti0 = Pr[jj] * f8.y + Pi[jj] * f8.x;
                Pr[jj] = tr0; Pi[jj] = ti0; Pr[jj + 1] = tr1; Pi[jj + 1] = ti1;
            }
        }
        {   // q9 -> element
            v4f f9 = coef(Q0 + 27, Aq[9], Cq[9]);
#pragma unroll
            for (int j = 0; j < 8; ++j) {
                float e0r = Pr[j] * f9.x - Pi[j] * f9.y;
                float e0i = Pr[j] * f9.y + Pi[j] * f9.x;
                float e1r = Pr[j] * f9.z - Pi[j] * f9.w;
                float e1i = Pr[j] * f9.w + Pi[j] * f9.z;
                sr[j] = pk2(e0r, e1r);
                si[j] = pk2(e0i, e1i);
            }
        }
    }
    cnot_ring_h(sr, si, lane, apm, a32);

    // ---------------- layers 1..3 (final ring absorbed into measurement) -----
#pragma unroll
    for (int l = 1; l < QL; ++l) {
        const v4f* Ql = Qg + l * NQ * 3;
        gate_lane_hp(sr, si, coef(Ql + 0,  Aq[0], Cq[0]), lane & 32, a32);
        gate_lane_hd<8>(sr, si, coef(Ql + 6,  Aq[2], Cq[2]), lane & 8);
        gate_lane_hp(sr, si, coef(Ql + 3,  Aq[1], Cq[1]), lane & 16, a16);
        gate_lane_hd<2>(sr, si, coef(Ql + 12, Aq[4], Cq[4]), lane & 2);
        gate_lane_hp(sr, si, coef(Ql + 9,  Aq[3], Cq[3]), lane & 4, a4);
        gate_lane_hd<1>(sr, si, coef(Ql + 15, Aq[5], Cq[5]), lane & 1);
        gate_reg_h<4>(sr, si, coef(Ql + 18, Aq[6], Cq[6]));
        gate_reg_h<2>(sr, si, coef(Ql + 21, Aq[7], Cq[7]));
        gate_reg_h<1>(sr, si, coef(Ql + 24, Aq[8], Cq[8]));
        gate_elem_h(sr, si, coef(Ql + 27, Aq[9], Cq[9]));
        if (l < QL - 1) cnot_ring_h(sr, si, lane, apm, a32);
    }

    // ---------------- measurement with ring-relabeled signs ------------------
    // Final basis bit of qubit k = prefix-XOR P_k = Q0^..^Qk of pre-ring bits;
    // qubit0 = Q1^..^Q9. Q0..Q5 = lane bits 5..0, Q6..Q8 = j bits 2..0, Q9 = e.
    v2f aP = {0.f, 0.f}, a6 = {0.f, 0.f}, a7 = {0.f, 0.f}, aT = {0.f, 0.f};
#pragma unroll
    for (int j = 0; j < 8; ++j) {
        v2f rr = {(float)sr[j].x, (float)sr[j].y};
        v2f ii = {(float)si[j].x, (float)si[j].y};
        v2f p = rr * rr + ii * ii;
        aP += p;
        a6 += (j & 4) ? -p : p;                               // j2
        a7 += ((((j >> 2) ^ (j >> 1)) & 1)) ? -p : p;         // j2^j1
        aT += ((((j >> 2) ^ (j >> 1) ^ j) & 1)) ? -p : p;     // j2^j1^j0
    }
    const float A0 = aP.x + aP.y;
    const float B6 = a6.x + a6.y;
    const float B7 = a7.x + a7.y;
    const float B8 = aT.x + aT.y;
    const float B9 = aT.x - aT.y;
    const bool P1 = __popc(lane & 0x30) & 1;
    const bool P2 = __popc(lane & 0x38) & 1;
    const bool P3 = __popc(lane & 0x3C) & 1;
    const bool P4 = __popc(lane & 0x3E) & 1;
    const bool P5 = __popc(lane & 0x3F) & 1;
    const bool PX = __popc(lane & 0x1F) & 1;   // for qubit0: P9 ^ Q0
    float z[NQ];
    z[0] = PX ? -B9 : B9;
    z[1] = P1 ? -A0 : A0;
    z[2] = P2 ? -A0 : A0;
    z[3] = P3 ? -A0 : A0;
    z[4] = P4 ? -A0 : A0;
    z[5] = P5 ? -A0 : A0;
    z[6] = P5 ? -B6 : B6;
    z[7] = P5 ? -B7 : B7;
    z[8] = P5 ? -B8 : B8;
    z[9] = P5 ? -B9 : B9;
    reduce10(z, a32, a16, a4);

    // ---------------- epilogue: out = x + z @ out_W^T + out_b ----------------
    v2f* orow2 = (v2f*)(out + (size_t)tok * DQ);
    const v2f* ob2 = (const v2f*)out_b;
    const v2f* oWt2 = (const v2f*)ws;   // transposed out_W [q][d]
#pragma unroll
    for (int k = 0; k < 4; ++k) {
        const int d2 = lane + 64 * k;
        v2f acc = xrow2[d2] + ob2[d2];
#pragma unroll
        for (int q = 0; q < NQ; ++q)
            acc = z[q] * oWt2[q * (DQ / 2) + d2] + acc;
        orow2[d2] = acc;
    }
}

extern "C" void kernel_launch(void* const* d_in, const int* in_sizes, int n_in,
                              void* d_out, int out_size, void* d_ws, size_t ws_size,
                              hipStream_t stream) {
    const float* x       = (const float*)d_in[0];
    const float* in_W    = (const float*)d_in[1];
    const float* in_b    = (const float*)d_in[2];
    const float* gamma   = (const float*)d_in[3];
    const float* beta    = (const float*)d_in[4];
    const float* weights = (const float*)d_in[5];
    const float* out_W   = (const float*)d_in[6];
    const float* out_b   = (const float*)d_in[7];
    float* out = (float*)d_out;
    float* ws = (float*)d_ws;

    hipLaunchKernelGGL(prep_kernel, dim3(1), dim3(512), 0, stream,
                       weights, out_W, ws);
    hipLaunchKernelGGL(quantum_kernel, dim3(NTOK / 4), dim3(256), 0, stream,
                       x, in_W, in_b, gamma, beta, ws, out_b, out);
}

// Round 9
// 189.001 us; speedup vs baseline: 1.2393x; 1.0345x over previous
//
#include <hip/hip_runtime.h>

// QuantumLayer: B=8, L=2048, D=512, NQ=10, 4 layers, DIM=1024.
// One wave per token. Statevector packed as half2: amplitude index i (10 bits):
//   lane = i>>4 (bits 9..4), reg r = i&15; r = 2*j + e (j = VGPR idx, e = half)
// qubit q at bit 9-q: q0..q5 -> lane bits 5..0; q6 -> j bit2, q7 -> j bit1,
// q8 -> j bit0, q9 -> element(half).
//
// Per layer/qubit RX(f)->phase(f)->RY(w0)->RZ(w1) fuse into one SU(2) gate
// (ar,ai,br,bi) = Q0 + A*Q1 + C*Q2, A=c^2, C=c*s. Q* weight-only, stored in
// d_ws BOTH as f32 (layer-0 product-state build) and packed f16 (layers 1..3
// coef math in v_pk_fma_f16). Final CNOT ring absorbed into measurement signs.
#define NQ 10
#define DQ 512
#define QL 4
#define NTOK (8 * 2048)
#define QOFF (NQ * DQ)          // float offset of f32 Q tables inside ws
#define QHOFF (QOFF + 480)      // float offset of f16 Q tables inside ws

typedef float v2f __attribute__((ext_vector_type(2)));
typedef float v4f __attribute__((ext_vector_type(4)));
typedef _Float16 h2 __attribute__((ext_vector_type(2)));

// ---- cross-lane helpers (all HW-proven in R7/R8) ---------------------------
__device__ __forceinline__ int bperm(int addr, int v) {
    return __builtin_amdgcn_ds_bpermute(addr, v);
}
__device__ __forceinline__ float bpermf(int addr, float v) {
    return __builtin_bit_cast(float, bperm(addr, __builtin_bit_cast(int, v)));
}
__device__ __forceinline__ h2 bpermh(int addr, h2 v) {
    return __builtin_bit_cast(h2, bperm(addr, __builtin_bit_cast(int, v)));
}
template <int CTRL>
__device__ __forceinline__ int dppi(int i) {
    return __builtin_amdgcn_update_dpp(i, i, CTRL, 0xF, 0xF, false);
}
template <int M>   // M in {1,2,8}
__device__ __forceinline__ float dppxf(float v) {
    int i = __builtin_bit_cast(int, v);
    if constexpr (M == 1)      i = dppi<0xB1>(i);   // quad_perm [1,0,3,2]
    else if constexpr (M == 2) i = dppi<0x4E>(i);   // quad_perm [2,3,0,1]
    else                       i = dppi<0x128>(i);  // row_ror:8 == xor 8
    return __builtin_bit_cast(float, i);
}
template <int M>   // M in {1,2,8}
__device__ __forceinline__ h2 dppxh(h2 v) {
    int i = __builtin_bit_cast(int, v);
    if constexpr (M == 1)      i = dppi<0xB1>(i);
    else if constexpr (M == 2) i = dppi<0x4E>(i);
    else                       i = dppi<0x128>(i);
    return __builtin_bit_cast(h2, i);
}

// f32 butterfly broadcast-reduce over 64 lanes (stage-1 h only)
__device__ __forceinline__ void reduce10(float* z, int a32, int a16, int a4) {
#pragma unroll
    for (int q = 0; q < NQ; ++q) {
        z[q] += bpermf(a32, z[q]);
        z[q] += bpermf(a16, z[q]);
        z[q] += dppxf<8>(z[q]);
        z[q] += bpermf(a4, z[q]);
        z[q] += dppxf<2>(z[q]);
        z[q] += dppxf<1>(z[q]);
    }
}

__device__ __forceinline__ h2 pk2(float a, float b) {
    return __builtin_bit_cast(h2, __builtin_amdgcn_cvt_pkrtz(a, b));
}
__device__ __forceinline__ h2 h2swap(h2 v) {
    return __builtin_shufflevector(v, v, 1, 0);
}
__device__ __forceinline__ h2 splat_lo(h2 v) {
    return __builtin_shufflevector(v, v, 0, 0);
}
__device__ __forceinline__ h2 splat_hi(h2 v) {
    return __builtin_shufflevector(v, v, 1, 1);
}

// f32 coef for layer-0 build: Q0 + A*Q1 + C*Q2
__device__ __forceinline__ v4f coef(const v4f* Q, float A, float C) {
    return Q[0] + A * Q[1] + C * Q[2];
}
// f16 coef for layers 1..3: per gate 6 h2 at Qg6 -> (arai, brbi)
__device__ __forceinline__ void coefh(const h2* Qg6, h2 A2, h2 C2,
                                      h2& arai, h2& brbi) {
    arai = Qg6[0] + A2 * Qg6[2] + C2 * Qg6[4];
    brbi = Qg6[1] + A2 * Qg6[3] + C2 * Qg6[5];
}

// ---- SU(2) gate application on f16-packed state (R8-verified math) ---------
__device__ __forceinline__ void gate_lane_hp(h2* sr, h2* si, h2 arai, h2 brbi,
                                             bool bit, int addr) {
    const h2 ar = splat_lo(arai), ai = splat_hi(arai);
    const h2 br = splat_lo(brbi), bi = splat_hi(brbi);
    const h2 Ai = bit ? -ai : ai;
    const h2 Br = bit ? br : -br;
#pragma unroll
    for (int j = 0; j < 8; ++j) {
        h2 wr = bpermh(addr, sr[j]), wi = bpermh(addr, si[j]);
        h2 nr = ar * sr[j] - Ai * si[j] + Br * wr - bi * wi;
        h2 ni = ar * si[j] + Ai * sr[j] + Br * wi + bi * wr;
        sr[j] = nr; si[j] = ni;
    }
}
template <int M>
__device__ __forceinline__ void gate_lane_hd(h2* sr, h2* si, h2 arai, h2 brbi,
                                             bool bit) {
    const h2 ar = splat_lo(arai), ai = splat_hi(arai);
    const h2 br = splat_lo(brbi), bi = splat_hi(brbi);
    const h2 Ai = bit ? -ai : ai;
    const h2 Br = bit ? br : -br;
#pragma unroll
    for (int j = 0; j < 8; ++j) {
        h2 wr = dppxh<M>(sr[j]), wi = dppxh<M>(si[j]);
        h2 nr = ar * sr[j] - Ai * si[j] + Br * wr - bi * wi;
        h2 ni = ar * si[j] + Ai * sr[j] + Br * wi + bi * wr;
        sr[j] = nr; si[j] = ni;
    }
}
template <int BJ>
__device__ __forceinline__ void gate_reg_h(h2* sr, h2* si, h2 arai, h2 brbi) {
    const h2 ar = splat_lo(arai), ai = splat_hi(arai);
    const h2 br = splat_lo(brbi), bi = splat_hi(brbi);
#pragma unroll
    for (int j = 0; j < 8; ++j) if (!(j & BJ)) {
        const int j1 = j | BJ;
        h2 x0r = sr[j], x0i = si[j], x1r = sr[j1], x1i = si[j1];
        sr[j]  = ar * x0r - ai * x0i - br * x1r - bi * x1i;
        si[j]  = ar * x0i + ai * x0r - br * x1i + bi * x1r;
        sr[j1] = br * x0r - bi * x0i + ar * x1r + ai * x1i;
        si[j1] = br * x0i + bi * x0r + ar * x1i - ai * x1r;
    }
}
__device__ __forceinline__ void gate_elem_h(h2* sr, h2* si, h2 arai, h2 brbi) {
    const h2 ar = splat_lo(arai), bi = splat_hi(brbi);
    // aiV = (ai, -ai): negate hi half; brV = (-br, br): negate lo half
    const h2 aiV = __builtin_bit_cast(h2,
        __builtin_bit_cast(int, splat_hi(arai)) ^ (int)0x80000000);
    const h2 brV = __builtin_bit_cast(h2,
        __builtin_bit_cast(int, splat_lo(brbi)) ^ 0x00008000);
#pragma unroll
    for (int j = 0; j < 8; ++j) {
        h2 swr = h2swap(sr[j]), swi = h2swap(si[j]);
        h2 nr = ar * sr[j] - aiV * si[j] + brV * swr - bi * swi;
        h2 ni = ar * si[j] + aiV * sr[j] + brV * swi + bi * swr;
        sr[j] = nr; si[j] = ni;
    }
}

// CNOT q=6,7,8 composed register permutation (R7/R8-proven)
__device__ __forceinline__ void perm678_h(h2* a) {
    h2 o2 = a[2], o4 = a[4], o7 = a[7];
    a[1] = h2swap(a[1]);
    a[2] = a[3]; a[3] = h2swap(o2);
    a[4] = a[6]; a[6] = a[5]; a[5] = h2swap(o7); a[7] = h2swap(o4);
}

// ring CNOTs q -> q+1 (mod 10) on f16-packed state (R8-proven)
__device__ __forceinline__ void cnot_ring_h(h2* sr, h2* si, int lane, int apm, int a32) {
#pragma unroll
    for (int j = 0; j < 8; ++j) {
        sr[j] = bpermh(apm, sr[j]);
        si[j] = bpermh(apm, si[j]);
    }
    {
        const bool ctrl = (lane & 1);
#pragma unroll
        for (int j = 0; j < 4; ++j) {
            h2 t0 = sr[j], t1 = sr[j + 4];
            sr[j] = ctrl ? t1 : t0; sr[j + 4] = ctrl ? t0 : t1;
            t0 = si[j]; t1 = si[j + 4];
            si[j] = ctrl ? t1 : t0; si[j + 4] = ctrl ? t0 : t1;
        }
    }
    perm678_h(sr);
    perm678_h(si);
#pragma unroll
    for (int j = 0; j < 8; ++j) {
        h2 w = bpermh(a32, sr[j]); sr[j] = (h2){sr[j].x, w.y};
        w = bpermh(a32, si[j]);    si[j] = (h2){si[j].x, w.y};
    }
}

// ---- prep kernel: transposed out_W + Q tables (f32 and packed f16) ---------
__global__ __launch_bounds__(512) void prep_kernel(
    const float* __restrict__ weights, const float* __restrict__ out_W,
    float* __restrict__ ws)
{
    const int t = threadIdx.x;   // 512 threads
#pragma unroll
    for (int q = 0; q < NQ; ++q)
        ws[q * DQ + t] = out_W[t * NQ + q];
    if (t < QL * NQ) {
        float w0 = weights[t * 2], w1 = weights[t * 2 + 1];
        float cy = __cosf(0.5f * w0), sy = __sinf(0.5f * w0);
        float cz = __cosf(0.5f * w1), sz = __sinf(0.5f * w1);
        float d = cy - sy, e = cy + sy;
        v4f q0 = (v4f){-cz * sy,  sz * sy,  cz * cy,  sz * cy};
        v4f q1 = (v4f){ cz * e,  -sz * e,  -cz * d,  -sz * d};
        v4f q2 = (v4f){-sz * d,  -cz * d,   sz * e,  -cz * e};
        v4f* Q = (v4f*)(ws + QOFF);
        Q[t * 3 + 0] = q0; Q[t * 3 + 1] = q1; Q[t * 3 + 2] = q2;
        h2* Qh = (h2*)(ws + QHOFF);
        Qh[t * 6 + 0] = pk2(q0.x, q0.y); Qh[t * 6 + 1] = pk2(q0.z, q0.w);
        Qh[t * 6 + 2] = pk2(q1.x, q1.y); Qh[t * 6 + 3] = pk2(q1.z, q1.w);
        Qh[t * 6 + 4] = pk2(q2.x, q2.y); Qh[t * 6 + 5] = pk2(q2.z, q2.w);
    }
}

__global__ __launch_bounds__(256) void quantum_kernel(
    const float* __restrict__ x, const float* __restrict__ in_W,
    const float* __restrict__ in_b, const float* __restrict__ gamma,
    const float* __restrict__ beta, const float* __restrict__ ws,
    const float* __restrict__ out_b, float* __restrict__ out)
{
    const int t = threadIdx.x;
    const int lane = t & 63;
    const int tok = blockIdx.x * 4 + (t >> 6);
    const v4f* Qg = (const v4f*)(ws + QOFF);    // f32 (layer 0)
    const h2*  Qh = (const h2*)(ws + QHOFF);    // f16 (layers 1..3)

    // hoisted bpermute byte addresses
    const int a32 = (lane ^ 32) << 2;
    const int a16 = (lane ^ 16) << 2;
    const int a4  = (lane ^ 4)  << 2;
    int srcl = lane;
#pragma unroll
    for (int q = 4; q >= 0; --q) {
        const int bc = 5 - q, bt = bc - 1;
        srcl ^= ((srcl >> bc) & 1) << bt;
    }
    const int apm = srcl << 2;

    // ---------------- stage 1: h = tanh(x @ in_W^T + in_b), then LN ----------
    const v4f* xrow4 = (const v4f*)(x + (size_t)tok * DQ);
    const v4f* inW4 = (const v4f*)in_W;
    v4f hv[NQ];
#pragma unroll
    for (int q = 0; q < NQ; ++q) hv[q] = (v4f){0.f, 0.f, 0.f, 0.f};
#pragma unroll
    for (int k = 0; k < 2; ++k) {
        v4f xk = xrow4[lane + 64 * k];
#pragma unroll
        for (int q = 0; q < NQ; ++q)
            hv[q] = xk * inW4[q * (DQ / 4) + lane + 64 * k] + hv[q];
    }
    float h[NQ];
#pragma unroll
    for (int q = 0; q < NQ; ++q)
        h[q] = (hv[q].x + hv[q].y) + (hv[q].z + hv[q].w);
    reduce10(h, a32, a16, a4);

    float mu = 0.f;
#pragma unroll
    for (int q = 0; q < NQ; ++q) {
        float e = __expf(2.f * (h[q] + in_b[q]));
        h[q] = (e - 1.f) * __builtin_amdgcn_rcpf(e + 1.f);
        mu += h[q];
    }
    mu *= 0.1f;
    float var = 0.f;
#pragma unroll
    for (int q = 0; q < NQ; ++q) { float d0 = h[q] - mu; var += d0 * d0; }
    var *= 0.1f;
    const float rstd = rsqrtf(var + 1e-5f);

    float Aq[NQ], Cq[NQ];
    h2 A2[NQ], C2[NQ];
#pragma unroll
    for (int q = 0; q < NQ; ++q) {
        float f = (h[q] - mu) * rstd * gamma[q] + beta[q];
        float hf = 0.5f * f;
        float c = __cosf(hf), s = __sinf(hf);
        Aq[q] = c * c;
        Cq[q] = c * s;
        A2[q] = pk2(Aq[q], Aq[q]);
        C2[q] = pk2(Cq[q], Cq[q]);
    }

    // ---------------- layer 0: product state built directly (fp32) ----------
    h2 sr[8], si[8];
    {
        const v4f* Q0 = Qg;
        v4f f0 = coef(Q0 + 0, Aq[0], Cq[0]);
        bool b0 = (lane & 32);
        float Lr = b0 ? f0.z : f0.x, Li = b0 ? f0.w : f0.y;
#pragma unroll
        for (int q = 1; q < 6; ++q) {
            v4f f = coef(Q0 + 3 * q, Aq[q], Cq[q]);
            bool b = lane & (1 << (5 - q));
            float fr = b ? f.z : f.x, fi = b ? f.w : f.y;
            float nr = Lr * fr - Li * fi, ni = Lr * fi + Li * fr;
            Lr = nr; Li = ni;
        }
        float Pr[8], Pi[8];
        {   // q6 -> j bit2
            v4f f6 = coef(Q0 + 18, Aq[6], Cq[6]);
            Pr[0] = Lr * f6.x - Li * f6.y; Pi[0] = Lr * f6.y + Li * f6.x;
            Pr[4] = Lr * f6.z - Li * f6.w; Pi[4] = Lr * f6.w + Li * f6.z;
        }
        {   // q7 -> j bit1
            v4f f7 = coef(Q0 + 21, Aq[7], Cq[7]);
#pragma unroll
            for (int jj = 0; jj < 8; jj += 4) {
                float tr1 = Pr[jj] * f7.z - Pi[jj] * f7.w;
                float ti1 = Pr[jj] * f7.w + Pi[jj] * f7.z;
                float tr0 = Pr[jj] * f7.x - Pi[jj] * f7.y;
                float ti0 = Pr[jj] * f7.y + Pi[jj] * f7.x;
                Pr[jj] = tr0; Pi[jj] = ti0; Pr[jj + 2] = tr1; Pi[jj + 2] = ti1;
            }
        }
        {   // q8 -> j bit0
            v4f f8 = coef(Q0 + 24, Aq[8], Cq[8]);
#pragma unroll
            for (int jj = 0; jj < 8; jj += 2) {
                float tr1 = Pr[jj] * f8.z - Pi[jj] * f8.w;
                float ti1 = Pr[jj] * f8.w + Pi[jj] * f8.z;
                float tr0 = Pr[jj] * f8.x - Pi[jj] * f8.y;
                float ti0 = Pr[jj] * f8.y + Pi[jj] * f8.x;
                Pr[jj] = tr0; Pi[jj] = ti0; Pr[jj + 1] = tr1; Pi[jj + 1] = ti1;
            }
        }
        {   // q9 -> element
            v4f f9 = coef(Q0 + 27, Aq[9], Cq[9]);
#pragma unroll
            for (int j = 0; j < 8; ++j) {
                float e0r = Pr[j] * f9.x - Pi[j] * f9.y;
                float e0i = Pr[j] * f9.y + Pi[j] * f9.x;
                float e1r = Pr[j] * f9.z - Pi[j] * f9.w;
                float e1i = Pr[j] * f9.w + Pi[j] * f9.z;
                sr[j] = pk2(e0r, e1r);
                si[j] = pk2(e0i, e1i);
            }
        }
    }
    cnot_ring_h(sr, si, lane, apm, a32);

    // ---------------- layers 1..3 (final ring absorbed into measurement) -----
#pragma unroll
    for (int l = 1; l < QL; ++l) {
        const h2* Ql = Qh + l * NQ * 6;
        h2 arai, brbi;
        coefh(Ql + 0 * 6, A2[0], C2[0], arai, brbi); gate_lane_hp(sr, si, arai, brbi, lane & 32, a32);
        coefh(Ql + 2 * 6, A2[2], C2[2], arai, brbi); gate_lane_hd<8>(sr, si, arai, brbi, lane & 8);
        coefh(Ql + 1 * 6, A2[1], C2[1], arai, brbi); gate_lane_hp(sr, si, arai, brbi, lane & 16, a16);
        coefh(Ql + 4 * 6, A2[4], C2[4], arai, brbi); gate_lane_hd<2>(sr, si, arai, brbi, lane & 2);
        coefh(Ql + 3 * 6, A2[3], C2[3], arai, brbi); gate_lane_hp(sr, si, arai, brbi, lane & 4, a4);
        coefh(Ql + 5 * 6, A2[5], C2[5], arai, brbi); gate_lane_hd<1>(sr, si, arai, brbi, lane & 1);
        coefh(Ql + 6 * 6, A2[6], C2[6], arai, brbi); gate_reg_h<4>(sr, si, arai, brbi);
        coefh(Ql + 7 * 6, A2[7], C2[7], arai, brbi); gate_reg_h<2>(sr, si, arai, brbi);
        coefh(Ql + 8 * 6, A2[8], C2[8], arai, brbi); gate_reg_h<1>(sr, si, arai, brbi);
        coefh(Ql + 9 * 6, A2[9], C2[9], arai, brbi); gate_elem_h(sr, si, arai, brbi);
        if (l < QL - 1) cnot_ring_h(sr, si, lane, apm, a32);
    }

    // ---------------- measurement (packed f16, ring-relabeled signs) ---------
    h2 aP = (h2){0, 0}, a6 = (h2){0, 0}, a7 = (h2){0, 0}, aT = (h2){0, 0};
#pragma unroll
    for (int j = 0; j < 8; ++j) {
        h2 p = sr[j] * sr[j] + si[j] * si[j];
        aP += p;
        if (j & 4) a6 -= p; else a6 += p;                        // j2
        if (((j >> 2) ^ (j >> 1)) & 1) a7 -= p; else a7 += p;    // j2^j1
        if (((j >> 2) ^ (j >> 1) ^ j) & 1) aT -= p; else aT += p;// j2^j1^j0
    }
    const float A0 = (float)aP.x + (float)aP.y;
    const float B6 = (float)a6.x + (float)a6.y;
    const float B7 = (float)a7.x + (float)a7.y;
    const float B8 = (float)aT.x + (float)aT.y;
    const float B9 = (float)aT.x - (float)aT.y;
    const bool P1 = __popc(lane & 0x30) & 1;
    const bool P2 = __popc(lane & 0x38) & 1;
    const bool P3 = __popc(lane & 0x3C) & 1;
    const bool P4 = __popc(lane & 0x3E) & 1;
    const bool P5 = __popc(lane & 0x3F) & 1;
    const bool PX = __popc(lane & 0x1F) & 1;   // qubit0: P9 ^ Q0
    float z[NQ];
    z[0] = PX ? -B9 : B9;
    z[1] = P1 ? -A0 : A0;
    z[2] = P2 ? -A0 : A0;
    z[3] = P3 ? -A0 : A0;
    z[4] = P4 ? -A0 : A0;
    z[5] = P5 ? -A0 : A0;
    z[6] = P5 ? -B6 : B6;
    z[7] = P5 ? -B7 : B7;
    z[8] = P5 ? -B8 : B8;
    z[9] = P5 ? -B9 : B9;

    // packed f16 butterfly broadcast-reduce of z (5 h2 regs, 6 steps)
    h2 zp[5];
#pragma unroll
    for (int i = 0; i < 5; ++i) zp[i] = pk2(z[2 * i], z[2 * i + 1]);
#pragma unroll
    for (int i = 0; i < 5; ++i) {
        zp[i] += bpermh(a32, zp[i]);
        zp[i] += bpermh(a16, zp[i]);
        zp[i] += dppxh<8>(zp[i]);
        zp[i] += bpermh(a4, zp[i]);
        zp[i] += dppxh<2>(zp[i]);
        zp[i] += dppxh<1>(zp[i]);
    }
    float zf[NQ];
#pragma unroll
    for (int i = 0; i < 5; ++i) {
        zf[2 * i]     = (float)zp[i].x;
        zf[2 * i + 1] = (float)zp[i].y;
    }

    // ---------------- epilogue: out = x + z @ out_W^T + out_b ----------------
    v4f* orow4 = (v4f*)(out + (size_t)tok * DQ);
    const v4f* ob4 = (const v4f*)out_b;
    const v4f* oWt4 = (const v4f*)ws;   // transposed out_W [q][d]
#pragma unroll
    for (int k = 0; k < 2; ++k) {
        const int d4 = lane + 64 * k;
        v4f acc = xrow4[d4] + ob4[d4];
#pragma unroll
        for (int q = 0; q < NQ; ++q)
            acc = zf[q] * oWt4[q * (DQ / 4) + d4] + acc;
        orow4[d4] = acc;
    }
}

extern "C" void kernel_launch(void* const* d_in, const int* in_sizes, int n_in,
                              void* d_out, int out_size, void* d_ws, size_t ws_size,
                              hipStream_t stream) {
    const float* x       = (const float*)d_in[0];
    const float* in_W    = (const float*)d_in[1];
    const float* in_b    = (const float*)d_in[2];
    const float* gamma   = (const float*)d_in[3];
    const float* beta    = (const float*)d_in[4];
    const float* weights = (const float*)d_in[5];
    const float* out_W   = (const float*)d_in[6];
    const float* out_b   = (const float*)d_in[7];
    float* out = (float*)d_out;
    float* ws = (float*)d_ws;

    hipLaunchKernelGGL(prep_kernel, dim3(1), dim3(512), 0, stream,
                       weights, out_W, ws);
    hipLaunchKernelGGL(quantum_kernel, dim3(NTOK / 4), dim3(256), 0, stream,
                       x, in_W, in_b, gamma, beta, ws, out_b, out);
}